// Round 6
// baseline (248.543 us; speedup 1.0000x reference)
//
#include <hip/hip_runtime.h>

typedef __attribute__((ext_vector_type(8))) short short8;
typedef __attribute__((ext_vector_type(4))) short short4v;
typedef __attribute__((ext_vector_type(16))) float float16;

#define NPIX_HID 8388608   // 8*64*128*128
#define ROWU 1170          // LDS units (16B) per halo row: 130 px * 9
#define ROWB 18720         // bytes per halo row
#define WS_NEED (589824u + 33554432u)

__device__ __forceinline__ short f2bf(float f) {
    union { float f; unsigned u; } v; v.f = f;
    unsigned r = (v.u + 0x7FFFu + ((v.u >> 16) & 1u)) >> 16;
    return (short)r;
}
__device__ __forceinline__ float sigmoidf_(float v) { return 1.f / (1.f + __expf(-v)); }
__device__ __forceinline__ float tanhf_(float v)    { return 2.f / (1.f + __expf(-2.f * v)) - 1.f; }

// ============================ FAST PATH ============================
// A layout: flat step st = (half*9+tap)*4+s; A[st*4096 + h*2048 + t*256 + r*8 + j]
// phys co = (r>>3)*64 + t*8 + (r&7);  ci = half*64 + s*16 + h*8 + j
__global__ void wprep2(const float* __restrict__ W, short* __restrict__ A) {
    int tid = blockIdx.x * 256 + threadIdx.x;
    if (tid >= 294912) return;
    int j = tid & 7, r = (tid >> 3) & 31, t = (tid >> 8) & 7;
    int h = (tid >> 11) & 1, s = (tid >> 12) & 3;
    int ht = tid >> 14;              // half*9 + tap
    int half = ht / 9, tap = ht - half * 9;
    int co = (r >> 3) * 64 + t * 8 + (r & 7);
    int ci = half * 64 + s * 16 + h * 8 + j;
    A[tid] = f2bf(W[co * 1152 + ci * 9 + tap]);
}

// fp32 NCHW (x, prev_h) -> bf16 Bprep[b][y][half][px][ci64]
__global__ void bprep_k(const float* __restrict__ x, const float* __restrict__ ph,
                        short* __restrict__ B) {
    int tid = blockIdx.x * 256 + threadIdx.x;    // 262144 threads
    int px = tid & 127;
    int yy = (tid >> 7) & 127;
    int half = (tid >> 14) & 1;
    int bb = tid >> 15;
    const float* src = half ? ph : x;
    const float* sp = src + ((size_t)(bb * 64) * 128 + yy) * 128 + px;
    short* dst = B + (size_t)(((bb * 128 + yy) * 2 + half)) * 8192 + px * 64;
#pragma unroll
    for (int oct = 0; oct < 8; ++oct) {
        short8 pk;
#pragma unroll
        for (int j = 0; j < 8; ++j) pk[j] = f2bf(sp[(oct * 8 + j) * 16384]);
        *(short8*)(dst + oct * 8) = pk;
    }
}

__global__ __launch_bounds__(256, 2) void convlstm_mainB(
    const short* __restrict__ bprep, const short* __restrict__ aprep,
    const float* __restrict__ pc, const float* __restrict__ bg,
    float* __restrict__ out)
{
    __shared__ short Bs[3 * ROWU * 8];   // 56160 B

    const int tid  = threadIdx.x;
    const int lane = tid & 63;
    const int wave = tid >> 6;
    const int l31  = lane & 31;
    const int h    = lane >> 5;
    const int mhalf = wave & 1;
    const int xhalf = wave >> 1;

    const int t  = blockIdx.x;       // 1024 = 8b * 128y
    const int y0 = t & 127;
    const int b  = t >> 7;

    float16 acc[4][2];
#pragma unroll
    for (int mt = 0; mt < 4; ++mt)
#pragma unroll
        for (int nt = 0; nt < 2; ++nt)
#pragma unroll
            for (int e = 0; e < 16; ++e) acc[mt][nt][e] = 0.f;

    const short* apl = aprep + h * 2048 + mhalf * 1024 + l31 * 8;
    short8 abuf[2][2][4];            // [parity][step-in-pair][mt]
#pragma unroll
    for (int ss = 0; ss < 2; ++ss)
#pragma unroll
        for (int mt = 0; mt < 4; ++mt)
            abuf[0][ss][mt] = *(const short8*)(apl + ss * 4096 + mt * 256);
    const short* apn = apl + 8192;   // next pair

    const int vb = ((xhalf * 64 + l31) * 9 + h) * 16;   // per-lane byte offset
    char* bsb = (char*)Bs;

#pragma unroll 1
    for (int phse = 0; phse < 2; ++phse) {
        if (phse) __syncthreads();
        // zero x-halo slots p=0, p=129 for all 3 rows
        if (tid < 48) {
            int r = tid >> 4, sd = (tid >> 3) & 1, oc = tid & 7;
            short8 z = {0,0,0,0,0,0,0,0};
            *(short8*)&Bs[(r * ROWU + sd * 129 * 9 + oc) * 8] = z;
        }
        // stage 3 halo rows of this ci-half (pure copy, no conversion)
#pragma unroll 1
        for (int r = 0; r < 3; ++r) {
            int ysrc = y0 + r - 1;
            if ((unsigned)ysrc < 128u) {
                const short* gsrc = bprep + (size_t)(((b * 128 + ysrc) * 2 + phse)) * 8192;
#pragma unroll
                for (int c = 0; c < 4; ++c) {
                    int k = c * 256 + tid;
                    int px = k >> 3, oc = k & 7;
                    short8 v = *(const short8*)(gsrc + k * 8);
                    *(short8*)&Bs[(r * ROWU + (px + 1) * 9 + oc) * 8] = v;
                }
            } else {
                short8 z = {0,0,0,0,0,0,0,0};
#pragma unroll
                for (int c = 0; c < 4; ++c) {
                    int k = c * 256 + tid;
                    int px = k >> 3, oc = k & 7;
                    *(short8*)&Bs[(r * ROWU + (px + 1) * 9 + oc) * 8] = z;
                }
            }
        }
        __syncthreads();

        // 9 taps; per tap two pairs (s=0,1 | s=2,3), parity compile-time
#pragma unroll 1
        for (int q2 = 0; q2 < 9; ++q2) {
            const int ky = q2 / 3;
            const int kx = q2 - ky * 3;
            const int ub = ky * ROWB + kx * 144;
            // ---- pair A (s=0,1): uses abuf[0]; prefetch abuf[1] ----
            {
#pragma unroll
                for (int ss = 0; ss < 2; ++ss)
#pragma unroll
                    for (int mt = 0; mt < 4; ++mt)
                        abuf[1][ss][mt] = *(const short8*)(apn + ss * 4096 + mt * 256);
                apn += 8192;
#pragma unroll
                for (int ss = 0; ss < 2; ++ss) {
                    short8 bfr[2];
#pragma unroll
                    for (int nt = 0; nt < 2; ++nt)
                        bfr[nt] = *(const short8*)(bsb + vb + (ub + nt * 4608 + ss * 32));
#pragma unroll
                    for (int mt = 0; mt < 4; ++mt)
#pragma unroll
                        for (int nt = 0; nt < 2; ++nt)
                            acc[mt][nt] = __builtin_amdgcn_mfma_f32_32x32x16_bf16(
                                abuf[0][ss][mt], bfr[nt], acc[mt][nt], 0, 0, 0);
                }
            }
            // ---- pair B (s=2,3): uses abuf[1]; prefetch abuf[0] ----
            {
                if (!((phse == 1) && (q2 == 8))) {
#pragma unroll
                    for (int ss = 0; ss < 2; ++ss)
#pragma unroll
                        for (int mt = 0; mt < 4; ++mt)
                            abuf[0][ss][mt] = *(const short8*)(apn + ss * 4096 + mt * 256);
                    apn += 8192;
                }
#pragma unroll
                for (int ss = 0; ss < 2; ++ss) {
                    const int s = 2 + ss;
                    short8 bfr[2];
#pragma unroll
                    for (int nt = 0; nt < 2; ++nt)
                        bfr[nt] = *(const short8*)(bsb + vb + (ub + nt * 4608 + s * 32));
#pragma unroll
                    for (int mt = 0; mt < 4; ++mt)
#pragma unroll
                        for (int nt = 0; nt < 2; ++nt)
                            acc[mt][nt] = __builtin_amdgcn_mfma_f32_32x32x16_bf16(
                                abuf[1][ss][mt], bfr[nt], acc[mt][nt], 0, 0, 0);
                }
            }
        }
    }

    // ---- fused gating epilogue (verified R5 mapping) ----
#pragma unroll
    for (int mt = 0; mt < 4; ++mt) {
        const int c0 = (mhalf * 4 + mt) * 8 + 4 * h;
#pragma unroll
        for (int nt = 0; nt < 2; ++nt) {
            const int px = xhalf * 64 + nt * 32 + l31;
#pragma unroll
            for (int a = 0; a < 4; ++a) {
                const int c = c0 + a;
                const float gi = acc[mt][nt][a]      + bg[c];
                const float gf = acc[mt][nt][4 + a]  + bg[64 + c];
                const float go = acc[mt][nt][8 + a]  + bg[128 + c];
                const float gc = acc[mt][nt][12 + a] + bg[192 + c];
                const float ig = sigmoidf_(gi);
                const float fg = sigmoidf_(gf);
                const float og = sigmoidf_(go);
                const float cg = tanhf_(gc);
                const int idx = ((b * 64 + c) * 128 + y0) * 128 + px;
                const float cell = ig * cg + fg * pc[idx];
                const float hid  = og * tanhf_(cell);
                out[idx] = hid;
                out[NPIX_HID + idx] = cell;
            }
        }
    }
}

// ============================ FALLBACK (verified R5) ============================
__global__ void wprep5(const float* __restrict__ W, short* __restrict__ A) {
    int tid = blockIdx.x * 256 + threadIdx.x;
    if (tid >= 9 * 16 * 8 * 32 * 8) return;
    int j = tid & 7, r = (tid >> 3) & 31, t = (tid >> 8) & 7;
    int cig = (tid >> 11) & 15, kk = tid >> 15;
    int g = r >> 3, cl = r & 7;
    int co = g * 64 + t * 8 + cl;
    int ci = cig * 8 + j;
    A[tid] = f2bf(W[co * 1152 + ci * 9 + kk]);
}

__global__ __launch_bounds__(256, 2) void convlstm_main5(
    const float* __restrict__ x, const float* __restrict__ ph,
    const float* __restrict__ pc, const short* __restrict__ aprep,
    const float* __restrict__ bg, float* __restrict__ out)
{
    __shared__ short Bs[4 * 66 * 128];
    const int tid = threadIdx.x, lane = tid & 63, wave = tid >> 6;
    const int l31 = lane & 31, h = lane >> 5;
    const int mhalf = wave & 1, nhalf = wave >> 1;
    const int t = blockIdx.x;
    const int x0 = (t & 1) * 64, y0 = ((t >> 1) & 63) * 2, b = t >> 7;

    for (int i = tid; i < 4224; i += 256) {
        const int px = i % 66, ro = i / 66, oct = ro & 15, row = ro >> 4;
        const int ysrc = y0 + row - 1, xsrc = x0 + px - 1;
        short8 pk = {0,0,0,0,0,0,0,0};
        if ((unsigned)ysrc < 128u && (unsigned)xsrc < 128u) {
            const float* src = (oct < 8) ? x : ph;
            const float* sp = src + (((b * 64 + (oct & 7) * 8) * 128 + ysrc) * 128 + xsrc);
#pragma unroll
            for (int j = 0; j < 8; ++j) pk[j] = f2bf(sp[j * 16384]);
        }
        const int off16 = (row * 66 + px) * 16 + (oct ^ (px & 15));
        *(short8*)&Bs[off16 * 8] = pk;
    }
    __syncthreads();

    float16 acc[4][2];
#pragma unroll
    for (int mt = 0; mt < 4; ++mt)
#pragma unroll
        for (int nt = 0; nt < 2; ++nt)
#pragma unroll
            for (int e = 0; e < 16; ++e) acc[mt][nt][e] = 0.f;

    const short* ap0 = aprep + h * 2048 + l31 * 8 + mhalf * 1024;
    const short* ap1 = ap0 + 4096;
    short8 abuf[2][2][4];
#pragma unroll
    for (int ks = 0; ks < 2; ++ks)
#pragma unroll
        for (int mt = 0; mt < 4; ++mt)
            abuf[0][ks][mt] = *(const short8*)((ks ? ap1 : ap0) + mt * 256);

#define HALF_BODY(KT, P, ADV)                                                      \
    {                                                                              \
        const int kt = (KT);                                                       \
        const int kkk = kt >> 2, kc = kt & 3;                                      \
        const int ky = (kkk * 11) >> 5;                                            \
        const int kx = kkk - ky * 3;                                               \
        if (ADV) { ap0 += 8192; ap1 += 8192;                                       \
            _Pragma("unroll")                                                      \
            for (int ks = 0; ks < 2; ++ks)                                         \
                _Pragma("unroll")                                                  \
                for (int mt = 0; mt < 4; ++mt)                                     \
                    abuf[(P) ^ 1][ks][mt] =                                        \
                        *(const short8*)((ks ? ap1 : ap0) + mt * 256);             \
        }                                                                          \
        const int pxb = kx + l31;                                                  \
        const int q = pxb & 15;                                                    \
        const int rh = ky + nhalf;                                                 \
        short8 bfr[2][2];                                                          \
        _Pragma("unroll")                                                          \
        for (int ks = 0; ks < 2; ++ks) {                                           \
            const int gx = ((kc * 4 + ks * 2) | h) ^ q;                            \
            _Pragma("unroll")                                                      \
            for (int nt = 0; nt < 2; ++nt) {                                       \
                const int off16 = (rh * 66 + nt * 32 + pxb) * 16 + gx;             \
                bfr[ks][nt] = *(const short8*)&Bs[off16 * 8];                      \
            }                                                                      \
        }                                                                          \
        _Pragma("unroll")                                                          \
        for (int mt = 0; mt < 4; ++mt)                                             \
            _Pragma("unroll")                                                      \
            for (int nt = 0; nt < 2; ++nt) {                                       \
                acc[mt][nt] = __builtin_amdgcn_mfma_f32_32x32x16_bf16(             \
                    abuf[P][0][mt], bfr[0][nt], acc[mt][nt], 0, 0, 0);             \
                acc[mt][nt] = __builtin_amdgcn_mfma_f32_32x32x16_bf16(             \
                    abuf[P][1][mt], bfr[1][nt], acc[mt][nt], 0, 0, 0);             \
            }                                                                      \
    }

#pragma unroll 1
    for (int it = 0; it < 18; ++it) {
        const int kt0 = it * 2;
        HALF_BODY(kt0, 0, 1)
        HALF_BODY(kt0 + 1, 1, (it < 17))
    }
#undef HALF_BODY

    const int yy = y0 + nhalf;
#pragma unroll
    for (int mt = 0; mt < 4; ++mt) {
        const int c0 = (mhalf * 4 + mt) * 8 + 4 * h;
#pragma unroll
        for (int nt = 0; nt < 2; ++nt) {
            const int px = x0 + nt * 32 + l31;
#pragma unroll
            for (int a = 0; a < 4; ++a) {
                const int c = c0 + a;
                const float gi = acc[mt][nt][a]      + bg[c];
                const float gf = acc[mt][nt][4 + a]  + bg[64 + c];
                const float go = acc[mt][nt][8 + a]  + bg[128 + c];
                const float gc = acc[mt][nt][12 + a] + bg[192 + c];
                const float ig = sigmoidf_(gi);
                const float fg = sigmoidf_(gf);
                const float og = sigmoidf_(go);
                const float cg = tanhf_(gc);
                const int idx = ((b * 64 + c) * 128 + yy) * 128 + px;
                const float cell = ig * cg + fg * pc[idx];
                const float hid  = og * tanhf_(cell);
                out[idx] = hid;
                out[NPIX_HID + idx] = cell;
            }
        }
    }
}

extern "C" void kernel_launch(void* const* d_in, const int* in_sizes, int n_in,
                              void* d_out, int out_size, void* d_ws, size_t ws_size,
                              hipStream_t stream) {
    const float* x  = (const float*)d_in[0];
    const float* ph = (const float*)d_in[1];
    const float* pc = (const float*)d_in[2];
    const float* W  = (const float*)d_in[3];
    const float* bg = (const float*)d_in[4];
    float* out = (float*)d_out;
    short* aprep = (short*)d_ws;                         // 589,824 B
    short* bprep = (short*)((char*)d_ws + 589824);       // 33,554,432 B

    if (ws_size >= (size_t)WS_NEED) {
        wprep2<<<1152, 256, 0, stream>>>(W, aprep);
        bprep_k<<<1024, 256, 0, stream>>>(x, ph, bprep);
        convlstm_mainB<<<1024, 256, 0, stream>>>(bprep, aprep, pc, bg, out);
    } else {
        wprep5<<<1152, 256, 0, stream>>>(W, aprep);
        convlstm_main5<<<1024, 256, 0, stream>>>(x, ph, pc, aprep, bg, out);
    }
}